// Round 2
// baseline (6342.156 us; speedup 1.0000x reference)
//
#include <hip/hip_runtime.h>
#include <math.h>

#define BATCH 64
#define LSAMP 524288
#define KLEN 1024
#define HOP 512
#define CBIN 513
#define TWIN 1027
#define BCT (64LL * 513 * 1027)   // 33718464

#define TT 32          // windows per block
#define TC 128         // freq bins per block
#define KC 64          // k-chunk
#define XSPAN (KLEN + (TT - 1) * HOP)   // 16896 floats
#define XUNITS (XSPAN / 4)               // 4224 float4
#define FBROWS (2 * TC)                  // 256 rows (real + imag)
#define FBUNITS (FBROWS * (KC / 4))      // 4096 float4
#define SMEM_BYTES (XSPAN * 4 + FBUNITS * 16)  // 133120

__global__ __launch_bounds__(512)
void stft_main(const float* __restrict__ x, const float* __restrict__ fb,
               float* __restrict__ out) {
    extern __shared__ float smem[];
    float*  xs  = smem;                                    // XSPAN floats
    float4* fbs = reinterpret_cast<float4*>(smem + XSPAN); // FBUNITS float4

    const int tid  = threadIdx.x;
    const int lane = tid & 63;
    const int w    = tid >> 6;
    const int cg   = w & 1;        // c-group 0/1
    const int tg   = w >> 1;       // t-group 0..3
    const int t0   = blockIdx.x * TT;        // 0..1024
    const int c0   = blockIdx.y * TC;        // 0,128,256,384
    const int b    = blockIdx.z;

    // ---- stage input window span (zero-padded), float4, aligned ----
    {
        const long g4start = ((long)t0 * HOP - KLEN) >> 2;   // 512-float aligned
        const float4* xg = reinterpret_cast<const float4*>(x + (size_t)b * LSAMP);
        for (int u = tid; u < XUNITS; u += 512) {
            long g = g4start + u;
            float4 v = make_float4(0.f, 0.f, 0.f, 0.f);
            if (g >= 0 && g < (LSAMP / 4)) v = xg[g];
            reinterpret_cast<float4*>(xs)[u] = v;
        }
    }

    const int crow   = cg * 64 + lane;    // 0..127 local freq row
    const int swz    = crow & 7;
    const int rbase  = crow * 16;         // float4-unit base of real row
    const int ibase  = (TC + crow) * 16;  // float4-unit base of imag row

    float re[8], im[8];
#pragma unroll
    for (int j = 0; j < 8; ++j) { re[j] = 0.f; im[j] = 0.f; }

    const float4* fbg = reinterpret_cast<const float4*>(fb);
    const float4* xr  = reinterpret_cast<const float4*>(xs);

    for (int kc = 0; kc < KLEN / KC; ++kc) {
        const int k0u = kc * (KC / 4);   // 16 units per chunk
        __syncthreads();
        // ---- stage fb chunk: 256 rows x 16 float4, XOR-swizzled ----
#pragma unroll
        for (int p = 0; p < 8; ++p) {
            int id  = p * 512 + tid;
            int row = id >> 4;
            int u   = id & 15;
            int gr  = (row < TC) ? (c0 + row) : (513 + c0 + (row - TC));
            float4 v = fbg[(size_t)gr * 256 + k0u + u];
            fbs[row * 16 + (u ^ (row & 7))] = v;
        }
        __syncthreads();

#pragma unroll 4
        for (int k4 = 0; k4 < 16; ++k4) {
            float4 fr = fbs[rbase + (k4 ^ swz)];
            float4 fi = fbs[ibase + (k4 ^ swz)];
#pragma unroll
            for (int j = 0; j < 8; ++j) {
                // wave-uniform address -> LDS broadcast
                float4 xv = xr[(tg * 8 + j) * 128 + k0u + k4];
                re[j] = fmaf(fr.x, xv.x, re[j]);
                re[j] = fmaf(fr.y, xv.y, re[j]);
                re[j] = fmaf(fr.z, xv.z, re[j]);
                re[j] = fmaf(fr.w, xv.w, re[j]);
                im[j] = fmaf(fi.x, xv.x, im[j]);
                im[j] = fmaf(fi.y, xv.y, im[j]);
                im[j] = fmaf(fi.z, xv.z, im[j]);
                im[j] = fmaf(fi.w, xv.w, im[j]);
            }
        }
    }

    // ---- epilogue: magnitude + phase ----
    const int c = c0 + crow;              // always < 512 here
    const size_t base = ((size_t)b * CBIN + c) * TWIN;
    const int tbase = t0 + tg * 8;
#pragma unroll
    for (int j = 0; j < 8; ++j) {
        int t = tbase + j;
        if (t < TWIN) {
            float m = sqrtf(fmaf(re[j], re[j], fmaf(im[j], im[j], 1e-10f)));
            float p = atan2f(im[j], re[j]);
            out[base + t]       = m;
            out[BCT + base + t] = p;
        }
    }
}

// Nyquist bin c=512: one wave per (b, t) output
__global__ __launch_bounds__(256)
void stft_nyq(const float* __restrict__ x, const float* __restrict__ fb,
              float* __restrict__ out) {
    const int gw   = (int)((blockIdx.x * 256 + threadIdx.x) >> 6);
    const int lane = threadIdx.x & 63;
    if (gw >= BATCH * TWIN) return;
    const int b = gw / TWIN;
    const int t = gw % TWIN;
    const long s = (long)t * HOP - KLEN;
    const float* xb = x + (size_t)b * LSAMP;
    const float* frow = fb + (size_t)512 * KLEN;
    const float* firow = fb + (size_t)1025 * KLEN;

    float re = 0.f, im = 0.f;
    for (int k = lane; k < KLEN; k += 64) {
        long g = s + k;
        float xv = (g >= 0 && g < LSAMP) ? xb[g] : 0.f;
        re = fmaf(xv, frow[k], re);
        im = fmaf(xv, firow[k], im);
    }
#pragma unroll
    for (int off = 32; off > 0; off >>= 1) {
        re += __shfl_down(re, off);
        im += __shfl_down(im, off);
    }
    if (lane == 0) {
        size_t base = ((size_t)b * CBIN + 512) * TWIN + t;
        out[base]       = sqrtf(fmaf(re, re, fmaf(im, im, 1e-10f)));
        out[BCT + base] = atan2f(im, re);
    }
}

// Cleanup pass: recompute branch-cut-risky points in fp64.
// Risky: phase within 4e-3 rad of the +/-pi cut, or magnitude so small
// that phase is pure accumulation noise.
__global__ __launch_bounds__(256)
void stft_fix(const float* __restrict__ x, const float* __restrict__ fb,
              float* __restrict__ out) {
    const long long n = BCT;
    const long long stride = (long long)gridDim.x * 256;
    for (long long i = (long long)blockIdx.x * 256 + threadIdx.x; i < n; i += stride) {
        float m = out[i];
        float p = out[BCT + i];
        bool risky = ((3.14159265f - fabsf(p)) < 4e-3f) || (m < 1e-4f);
        if (!risky) continue;

        int b  = (int)(i / (513LL * 1027));
        int rr = (int)(i % (513LL * 1027));
        int c  = rr / 1027;
        int t  = rr % 1027;

        const float* xb = x + (size_t)b * LSAMP;
        const float* fr = fb + (size_t)c * KLEN;
        const float* fi = fb + (size_t)(513 + c) * KLEN;

        const long s = (long)t * HOP - KLEN;
        int klo = 0, khi = KLEN;
        if (s < 0) klo = (int)(-s);
        if (s + KLEN > LSAMP) khi = (int)(LSAMP - s);

        double re = 0.0, im = 0.0;
        for (int k = klo; k < khi; ++k) {
            double xv = (double)xb[s + k];
            re = fma((double)fr[k], xv, re);
            im = fma((double)fi[k], xv, im);
        }
        double mag = sqrt(re * re + im * im + 1e-10);
        double ph  = atan2(im, re);
        out[i]       = (float)mag;
        out[BCT + i] = (float)ph;
    }
}

extern "C" void kernel_launch(void* const* d_in, const int* in_sizes, int n_in,
                              void* d_out, int out_size, void* d_ws, size_t ws_size,
                              hipStream_t stream) {
    const float* x  = (const float*)d_in[0];
    const float* fb = (const float*)d_in[1];
    float* out = (float*)d_out;

    dim3 grid((TWIN + TT - 1) / TT, /*c-tiles*/ 4, BATCH);   // 33 x 4 x 64
    stft_main<<<grid, 512, SMEM_BYTES, stream>>>(x, fb, out);

    int nwaves = BATCH * TWIN;                                // 65728
    int nblk = (nwaves * 64 + 255) / 256;                     // 16432
    stft_nyq<<<nblk, 256, 0, stream>>>(x, fb, out);

    stft_fix<<<8192, 256, 0, stream>>>(x, fb, out);
}

// Round 3
// 1144.187 us; speedup vs baseline: 5.5429x; 5.5429x over previous
//
#include <hip/hip_runtime.h>
#include <math.h>

#define BATCH 64
#define LSAMP 524288
#define KLEN 1024
#define HOP 512
#define CBIN 513
#define TWIN 1027
#define BCT (64LL * 513 * 1027)   // 33718464

using short8 = __attribute__((ext_vector_type(8))) short;
using f32x4  = __attribute__((ext_vector_type(4))) float;

__device__ inline ushort bfh(float v) {
    unsigned u = __float_as_uint(v);
    unsigned r = (u + 0x7fffu + ((u >> 16) & 1u)) >> 16;   // RNE
    return (ushort)r;
}
__device__ inline float bf2f(ushort h) { return __uint_as_float(((unsigned)h) << 16); }

__device__ inline float4 ldx4(const float* xb, long base) {
    // base is a multiple of 4 and LSAMP is a multiple of 4 -> float4 fully in or out
    if (base >= 0 && base < LSAMP) return *(const float4*)(xb + base);
    return make_float4(0.f, 0.f, 0.f, 0.f);
}

// ---------------- main GEMM: bf16x2 split-precision MFMA ----------------
// Block: 256 thr (4 waves: wm in {0,1} = re/im half, wn in {0,1}).
// Tile: M=128 rows (64 re + 64 im for c in [c0,c0+64)) x N=128 windows, K-step 32.
__global__ __launch_bounds__(256)
void stft_gemm(const float* __restrict__ x, const float* __restrict__ fb,
               float* __restrict__ out) {
    // staging: AH | AL | BH | BL, each 128x32 ushort (8KB) = 32KB total
    __shared__ ushort sm[16384];
    ushort* AH = sm;
    ushort* AL = sm + 4096;
    ushort* BH = sm + 8192;
    ushort* BL = sm + 12288;

    const int tid  = threadIdx.x;
    const int lane = tid & 63;
    const int w    = tid >> 6;
    const int wm   = w >> 1;       // 0: re rows, 1: im rows
    const int wn   = w & 1;
    const int lm   = lane & 15;
    const int lk   = (lane >> 4) * 8;    // k offset within 32

    const int ct = blockIdx.x;           // 0..7  -> c0
    const int nt = blockIdx.y;           // 0..8  -> n0
    const int b  = blockIdx.z;
    const int c0 = ct * 64;
    const int n0 = nt * 128;

    const float4* fbg = (const float4*)fb;          // row stride 256 float4
    const float*  xb  = x + (size_t)b * LSAMP;

    // per-thread staging coords: id = p*256+tid, row = id>>3, u = id&7
    int srow[4], su[4], sfbrow[4];
    long sxbase0[4];
#pragma unroll
    for (int p = 0; p < 4; ++p) {
        int id = p * 256 + tid;
        int row = id >> 3, u = id & 7;
        srow[p] = row; su[p] = u;
        sfbrow[p] = (row < 64) ? (c0 + row) : (513 + c0 + (row - 64));
        sxbase0[p] = 512L * (n0 + row) + 4L * u - 1024L;
    }

    f32x4 acc[4][4];
#pragma unroll
    for (int i = 0; i < 4; ++i)
#pragma unroll
        for (int j = 0; j < 4; ++j) acc[i][j] = (f32x4)0.f;

    float4 pa[4], pb[4];
    // prologue: load K-step 0
#pragma unroll
    for (int p = 0; p < 4; ++p) {
        pa[p] = fbg[(size_t)sfbrow[p] * 256 + su[p]];
        pb[p] = ldx4(xb, sxbase0[p]);
    }

    for (int ks = 0; ks < 32; ++ks) {
        __syncthreads();   // previous frag reads done, LDS free
        // write staged regs -> LDS with bf16 hi/lo split
#pragma unroll
        for (int p = 0; p < 4; ++p) {
            int o = srow[p] * 32 + su[p] * 4;
            float4 va = pa[p], vb = pb[p];
            ushort4 h, l;
            h.x = bfh(va.x); l.x = bfh(va.x - bf2f(h.x));
            h.y = bfh(va.y); l.y = bfh(va.y - bf2f(h.y));
            h.z = bfh(va.z); l.z = bfh(va.z - bf2f(h.z));
            h.w = bfh(va.w); l.w = bfh(va.w - bf2f(h.w));
            *(ushort4*)&AH[o] = h; *(ushort4*)&AL[o] = l;
            h.x = bfh(vb.x); l.x = bfh(vb.x - bf2f(h.x));
            h.y = bfh(vb.y); l.y = bfh(vb.y - bf2f(h.y));
            h.z = bfh(vb.z); l.z = bfh(vb.z - bf2f(h.z));
            h.w = bfh(vb.w); l.w = bfh(vb.w - bf2f(h.w));
            *(ushort4*)&BH[o] = h; *(ushort4*)&BL[o] = l;
        }
        __syncthreads();

        // prefetch next K-step (in flight during MFMAs)
        if (ks < 31) {
            int k0n = (ks + 1) * 32;
#pragma unroll
            for (int p = 0; p < 4; ++p) {
                pa[p] = fbg[(size_t)sfbrow[p] * 256 + (k0n >> 2) + su[p]];
                pb[p] = ldx4(xb, sxbase0[p] + k0n);
            }
        }

        // fragment loads
        short8 ah[4], al[4], bh[4], bl[4];
#pragma unroll
        for (int mi = 0; mi < 4; ++mi) {
            int o = (wm * 64 + mi * 16 + lm) * 32 + lk;
            ah[mi] = *(const short8*)&AH[o];
            al[mi] = *(const short8*)&AL[o];
        }
#pragma unroll
        for (int ni = 0; ni < 4; ++ni) {
            int o = (wn * 64 + ni * 16 + lm) * 32 + lk;
            bh[ni] = *(const short8*)&BH[o];
            bl[ni] = *(const short8*)&BL[o];
        }
        // 3-pass bf16x2: hh, hl, lh
#pragma unroll
        for (int mi = 0; mi < 4; ++mi)
#pragma unroll
            for (int ni = 0; ni < 4; ++ni)
                acc[mi][ni] = __builtin_amdgcn_mfma_f32_16x16x32_bf16(ah[mi], bh[ni], acc[mi][ni], 0, 0, 0);
#pragma unroll
        for (int mi = 0; mi < 4; ++mi)
#pragma unroll
            for (int ni = 0; ni < 4; ++ni)
                acc[mi][ni] = __builtin_amdgcn_mfma_f32_16x16x32_bf16(ah[mi], bl[ni], acc[mi][ni], 0, 0, 0);
#pragma unroll
        for (int mi = 0; mi < 4; ++mi)
#pragma unroll
            for (int ni = 0; ni < 4; ++ni)
                acc[mi][ni] = __builtin_amdgcn_mfma_f32_16x16x32_bf16(al[mi], bh[ni], acc[mi][ni], 0, 0, 0);
    }

    // ---------------- epilogue: pair re/im via LDS, two n-halves ----------------
    float* epsRe = (float*)sm;            // 64 x 64 f32 = 16KB
    float* epsIm = (float*)(sm + 8192);   // 16KB
#pragma unroll
    for (int h = 0; h < 2; ++h) {
        __syncthreads();
#pragma unroll
        for (int mi = 0; mi < 4; ++mi)
#pragma unroll
            for (int nj = 0; nj < 2; ++nj) {
                int ni = 2 * h + nj;
#pragma unroll
                for (int r = 0; r < 4; ++r) {
                    int cr   = mi * 16 + (lane >> 4) * 4 + r;
                    int nbuf = wn * 32 + nj * 16 + lm;
                    if (wm == 0) epsRe[cr * 64 + nbuf] = acc[mi][ni][r];
                    else         epsIm[cr * 64 + nbuf] = acc[mi][ni][r];
                }
            }
        __syncthreads();
        // all 256 threads: 4096 points, 16 each
#pragma unroll
        for (int q = 0; q < 16; ++q) {
            int id   = q * 256 + tid;
            int cr   = id >> 6;
            int nbuf = id & 63;
            int nr   = (nbuf >> 5) * 64 + h * 32 + (nbuf & 31);
            int n    = n0 + nr;
            if (n < TWIN) {
                float re = epsRe[cr * 64 + nbuf];
                float im = epsIm[cr * 64 + nbuf];
                size_t base = ((size_t)b * CBIN + (c0 + cr)) * TWIN + n;
                out[base]       = sqrtf(fmaf(re, re, fmaf(im, im, 1e-10f)));
                out[BCT + base] = atan2f(im, re);
            }
        }
    }
}

// ---------------- Nyquist bin c=512 ----------------
__global__ __launch_bounds__(256)
void stft_nyq(const float* __restrict__ x, const float* __restrict__ fb,
              float* __restrict__ out) {
    const int gw   = (int)((blockIdx.x * 256 + threadIdx.x) >> 6);
    const int lane = threadIdx.x & 63;
    if (gw >= BATCH * TWIN) return;
    const int b = gw / TWIN;
    const int t = gw % TWIN;
    const long s = (long)t * HOP - KLEN;
    const float* xb = x + (size_t)b * LSAMP;
    const float* frow  = fb + (size_t)512 * KLEN;
    const float* firow = fb + (size_t)1025 * KLEN;

    float re = 0.f, im = 0.f;
    for (int k = lane; k < KLEN; k += 64) {
        long g = s + k;
        float xv = (g >= 0 && g < LSAMP) ? xb[g] : 0.f;
        re = fmaf(xv, frow[k], re);
        im = fmaf(xv, firow[k], im);
    }
#pragma unroll
    for (int off = 32; off > 0; off >>= 1) {
        re += __shfl_down(re, off);
        im += __shfl_down(im, off);
    }
    if (lane == 0) {
        size_t base = ((size_t)b * CBIN + 512) * TWIN + t;
        out[base]       = sqrtf(fmaf(re, re, fmaf(im, im, 1e-10f)));
        out[BCT + base] = atan2f(im, re);
    }
}

// ---------------- branch-cut cleanup: scan + wave-cooperative fp64 recompute ----
__global__ __launch_bounds__(256)
void stft_fix(const float* __restrict__ x, const float* __restrict__ fb,
              float* __restrict__ out) {
    const long long stride = (long long)gridDim.x * 256;
    const int lane = threadIdx.x & 63;
    // BCT % 64 == 0 and wave bases are 64-aligned -> loop condition is wave-uniform
    for (long long i = (long long)blockIdx.x * 256 + threadIdx.x; i < BCT; i += stride) {
        float m = out[i];
        float p = out[BCT + i];
        bool risky = ((3.14159265f - fabsf(p)) * m < 3e-3f) || (m < 2e-3f);
        unsigned long long mask = __ballot(risky);
        while (mask) {
            int src = __ffsll(mask) - 1;
            mask &= mask - 1;
            long long idx = (i - lane) + src;   // i = wavebase + lane
            int bb = (int)(idx / (513LL * 1027));
            int rr = (int)(idx % (513LL * 1027));
            int c  = rr / 1027;
            int t  = rr % 1027;
            const float* xb = x + (size_t)bb * LSAMP;
            const float* fr = fb + (size_t)c * KLEN;
            const float* fi = fb + (size_t)(513 + c) * KLEN;
            const long s = (long)t * HOP - KLEN;
            double re = 0.0, im = 0.0;
            for (int k = lane; k < KLEN; k += 64) {
                long g = s + k;
                double xv = (g >= 0 && g < LSAMP) ? (double)xb[g] : 0.0;
                re = fma((double)fr[k], xv, re);
                im = fma((double)fi[k], xv, im);
            }
#pragma unroll
            for (int off = 32; off > 0; off >>= 1) {
                re += __shfl_down(re, off);
                im += __shfl_down(im, off);
            }
            if (lane == 0) {
                out[idx]       = (float)sqrt(re * re + im * im + 1e-10);
                out[BCT + idx] = (float)atan2(im, re);
            }
        }
    }
}

extern "C" void kernel_launch(void* const* d_in, const int* in_sizes, int n_in,
                              void* d_out, int out_size, void* d_ws, size_t ws_size,
                              hipStream_t stream) {
    const float* x  = (const float*)d_in[0];
    const float* fb = (const float*)d_in[1];
    float* out = (float*)d_out;

    dim3 grid(8, 9, BATCH);   // c-tiles x n-tiles x batch = 4608 blocks
    stft_gemm<<<grid, 256, 0, stream>>>(x, fb, out);

    int nwaves = BATCH * TWIN;
    int nblk = (nwaves * 64 + 255) / 256;
    stft_nyq<<<nblk, 256, 0, stream>>>(x, fb, out);

    stft_fix<<<2048, 256, 0, stream>>>(x, fb, out);
}

// Round 4
// 1042.991 us; speedup vs baseline: 6.0807x; 1.0970x over previous
//
#include <hip/hip_runtime.h>
#include <math.h>

#define BATCH 64
#define LSAMP 524288
#define KLEN 1024
#define HOP 512
#define CBIN 513
#define TWIN 1027
#define BCT (64LL * 513 * 1027)   // 33718464

typedef unsigned int uint32;
typedef unsigned short ushort16;
using short8  = __attribute__((ext_vector_type(8))) short;
using ushort8v= __attribute__((ext_vector_type(8))) unsigned short;
using f32x4   = __attribute__((ext_vector_type(4))) float;

// ---- workspace layout (ushort element offsets) ----
#define FBT_SLOTS (9 * 32 * 512)                 // 147456 slots of 8 ushorts
#define FBH_OFF 0u
#define FBL_OFF ((uint32)FBT_SLOTS * 8u)         // 1179648
#define XPLANE  526336                           // 1024 pad + 524288 + 1024 pad
#define XH_OFF  (2u * (uint32)FBT_SLOTS * 8u)    // 2359296
#define XL_OFF  (XH_OFF + 64u * (uint32)XPLANE)  // 36044800
#define WS_NEED ((size_t)(XL_OFF + 64u * (uint32)XPLANE) * 2)  // 139,460,608 B

__device__ __forceinline__ unsigned short bfh(float v) {
    uint32 u = __float_as_uint(v);
    return (unsigned short)((u + 0x7fffu + ((u >> 16) & 1u)) >> 16);   // RNE
}
__device__ __forceinline__ float bf2f(unsigned short h) {
    return __uint_as_float(((uint32)h) << 16);
}

__device__ __forceinline__ void gld16(const void* g, void* l) {
    using GT = const __attribute__((address_space(1))) unsigned int;
    using LT = __attribute__((address_space(3))) unsigned int;
    __builtin_amdgcn_global_load_lds((GT*)g, (LT*)l, 16, 0, 0);
}

// ---------------- pre-pass: split fb into pre-swizzled bf16 hi/lo tiles ----------------
__global__ __launch_bounds__(256)
void split_fb(const float* __restrict__ fb, unsigned short* __restrict__ ws) {
    int id = blockIdx.x * 256 + threadIdx.x;
    if (id >= FBT_SLOTS) return;
    int slot = id & 511;
    int tile = id >> 9;          // ct*32 + ks
    int ks = tile & 31;
    int ct = tile >> 5;
    int row = slot >> 2;
    int unit = (slot & 3) ^ ((row >> 1) & 3);   // logical k-unit stored at this slot
    int c0 = (ct < 8) ? ct * 64 : 449;
    int c = (row < 64) ? (c0 + row) : (513 + c0 + (row - 64));
    int k0 = ks * 32 + unit * 8;
    const float4* src = (const float4*)(fb + (size_t)c * KLEN + k0);
    float4 a = src[0], b = src[1];
    float vv[8] = {a.x, a.y, a.z, a.w, b.x, b.y, b.z, b.w};
    ushort8v hh, ll;
#pragma unroll
    for (int j = 0; j < 8; ++j) {
        unsigned short h = bfh(vv[j]);
        hh[j] = h;
        ll[j] = bfh(vv[j] - bf2f(h));
    }
    *(ushort8v*)&ws[FBH_OFF + (size_t)id * 8] = hh;
    *(ushort8v*)&ws[FBL_OFF + (size_t)id * 8] = ll;
}

// ---------------- pre-pass: split x into zero-padded bf16 hi/lo planes ----------------
__global__ __launch_bounds__(256)
void split_x(const float* __restrict__ x, unsigned short* __restrict__ ws) {
    long i = (long)blockIdx.x * 256 + threadIdx.x;
    if (i >= 64L * (XPLANE / 8)) return;
    int b = (int)(i / (XPLANE / 8));
    int j = (int)(i % (XPLANE / 8)) * 8;      // plane element offset, 8-aligned
    long sample = (long)j - 1024;
    float vv[8] = {0.f,0.f,0.f,0.f,0.f,0.f,0.f,0.f};
    if (sample >= 0 && sample < LSAMP) {
        const float4* s = (const float4*)(x + (size_t)b * LSAMP + sample);
        float4 a = s[0], c = s[1];
        vv[0]=a.x; vv[1]=a.y; vv[2]=a.z; vv[3]=a.w;
        vv[4]=c.x; vv[5]=c.y; vv[6]=c.z; vv[7]=c.w;
    }
    ushort8v hh, ll;
#pragma unroll
    for (int jj = 0; jj < 8; ++jj) {
        unsigned short h = bfh(vv[jj]);
        hh[jj] = h;
        ll[jj] = bfh(vv[jj] - bf2f(h));
    }
    *(ushort8v*)&ws[(size_t)XH_OFF + (size_t)b * XPLANE + j] = hh;
    *(ushort8v*)&ws[(size_t)XL_OFF + (size_t)b * XPLANE + j] = ll;
}

// ---------------- main GEMM: gload_lds staging, dbuf 2-phase, bf16x2 MFMA ----------------
// grid: flat 5184 = 8 xcd * (9 ct * 72); 9 ct-blocks of one (nt,b) group share an XCD.
// dynamic LDS: 67584 B (dbuf 2x32KB for K-loop; 2x64x132 f32 for epilogue)
__global__ __launch_bounds__(256, 2)
void stft_gemm(const unsigned short* __restrict__ ws, float* __restrict__ out) {
    extern __shared__ unsigned short sm[];

    const int tid  = threadIdx.x;
    const int lane = tid & 63;
    const int w    = tid >> 6;
    const int wm   = w >> 1;          // 0: re rows, 1: im rows
    const int wn   = w & 1;
    const int lm   = lane & 15;
    const int lg   = lane >> 4;
    const int swz  = (lm >> 1) & 3;

    const int p   = blockIdx.x;
    const int xcd = p & 7;
    const int q   = p >> 3;
    const int ct  = q % 9;
    const int g   = (q / 9) * 8 + xcd;
    const int nt  = g % 9;
    const int b   = g / 9;
    const int c0  = (ct < 8) ? ct * 64 : 449;
    const int n0  = nt * 128;

    f32x4 acc[4][4];
#pragma unroll
    for (int i = 0; i < 4; ++i)
#pragma unroll
        for (int j = 0; j < 4; ++j) acc[i][j] = (f32x4)0.f;

    // stage one 128x32 bf16 tile set (AH|AL|BH|BL, 8KB each) into buffer d for K-step ks
    auto STAGE = [&](int d, int ks) {
        const int s0 = w * 128;
        const uint32 atile = (uint32)(ct * 32 + ks) * 4096u;   // ushort idx of tile
#pragma unroll
        for (int r = 0; r < 2; ++r) {
            const int sbase = s0 + r * 64;
            const uint32 slot = (uint32)(sbase + lane);
            const uint32 dsto = (uint32)d * 16384u + (uint32)sbase * 8u;
            gld16(&ws[atile + slot * 8u],            &sm[dsto]);            // AH (FBH_OFF=0)
            gld16(&ws[FBL_OFF + atile + slot * 8u],  &sm[dsto + 4096u]);    // AL
            const uint32 brow  = slot >> 2;
            const uint32 bunit = (slot & 3u) ^ ((brow >> 1) & 3u);
            uint32 pidx = (uint32)(n0 + brow) * 512u + (uint32)ks * 32u + bunit * 8u;
            if (pidx > (uint32)(XPLANE - 8)) pidx = (uint32)(XPLANE - 8);  // n>=1027 junk, discarded
            gld16(&ws[(size_t)XH_OFF + (size_t)b * XPLANE + pidx], &sm[dsto + 8192u]);   // BH
            gld16(&ws[(size_t)XL_OFF + (size_t)b * XPLANE + pidx], &sm[dsto + 12288u]);  // BL
        }
    };

    STAGE(0, 0);
    __syncthreads();   // compiler drains vmcnt before s_barrier

    for (int ks = 0; ks < 32; ++ks) {
        const int cur = ks & 1;
        if (ks < 31) STAGE(cur ^ 1, ks + 1);   // prefetch in flight during ds_read+MFMA

        const uint32 base = (uint32)cur * 16384u;
        short8 ah[4], al[4], bh[4], bl[4];
#pragma unroll
        for (int mi = 0; mi < 4; ++mi) {
            const uint32 row = (uint32)(wm * 64 + mi * 16 + lm);
            const uint32 o = base + row * 32u + (uint32)((lg ^ swz) * 8);
            ah[mi] = *(const short8*)&sm[o];
            al[mi] = *(const short8*)&sm[o + 4096u];
        }
#pragma unroll
        for (int ni = 0; ni < 4; ++ni) {
            const uint32 row = (uint32)(wn * 64 + ni * 16 + lm);
            const uint32 o = base + 8192u + row * 32u + (uint32)((lg ^ swz) * 8);
            bh[ni] = *(const short8*)&sm[o];
            bl[ni] = *(const short8*)&sm[o + 4096u];
        }
        // 3-pass bf16x2: hh, hl, lh
#pragma unroll
        for (int mi = 0; mi < 4; ++mi)
#pragma unroll
            for (int ni = 0; ni < 4; ++ni)
                acc[mi][ni] = __builtin_amdgcn_mfma_f32_16x16x32_bf16(ah[mi], bh[ni], acc[mi][ni], 0, 0, 0);
#pragma unroll
        for (int mi = 0; mi < 4; ++mi)
#pragma unroll
            for (int ni = 0; ni < 4; ++ni)
                acc[mi][ni] = __builtin_amdgcn_mfma_f32_16x16x32_bf16(ah[mi], bl[ni], acc[mi][ni], 0, 0, 0);
#pragma unroll
        for (int mi = 0; mi < 4; ++mi)
#pragma unroll
            for (int ni = 0; ni < 4; ++ni)
                acc[mi][ni] = __builtin_amdgcn_mfma_f32_16x16x32_bf16(al[mi], bh[ni], acc[mi][ni], 0, 0, 0);

        __syncthreads();
    }

    // ---------------- epilogue: exchange re/im, mag+phase ----------------
    float* eps = (float*)sm;   // [2][64][132] f32, stride 132 -> 2-way-max banks
#pragma unroll
    for (int mi = 0; mi < 4; ++mi)
#pragma unroll
        for (int ni = 0; ni < 4; ++ni)
#pragma unroll
            for (int r = 0; r < 4; ++r) {
                int cr = mi * 16 + lg * 4 + r;
                int nc = wn * 64 + ni * 16 + lm;
                eps[wm * 8448 + cr * 132 + nc] = acc[mi][ni][r];
            }
    __syncthreads();
#pragma unroll 4
    for (int qq = 0; qq < 32; ++qq) {
        int id = qq * 256 + tid;
        int cr = id >> 7, nc = id & 127;
        int n = n0 + nc;
        if (n < TWIN) {
            float re = eps[cr * 132 + nc];
            float im = eps[8448 + cr * 132 + nc];
            size_t obase = ((size_t)b * CBIN + (c0 + cr)) * TWIN + n;
            out[obase]       = sqrtf(fmaf(re, re, fmaf(im, im, 1e-10f)));
            out[BCT + obase] = atan2f(im, re);
        }
    }
}

// ---------------- branch-cut cleanup (unchanged from R3, validated) ----------------
__global__ __launch_bounds__(256)
void stft_fix(const float* __restrict__ x, const float* __restrict__ fb,
              float* __restrict__ out) {
    const long long stride = (long long)gridDim.x * 256;
    const int lane = threadIdx.x & 63;
    for (long long i = (long long)blockIdx.x * 256 + threadIdx.x; i < BCT; i += stride) {
        float m = out[i];
        float p = out[BCT + i];
        bool risky = ((3.14159265f - fabsf(p)) * m < 3e-3f) || (m < 2e-3f);
        unsigned long long mask = __ballot(risky);
        while (mask) {
            int src = __ffsll(mask) - 1;
            mask &= mask - 1;
            long long idx = (i - lane) + src;
            int bb = (int)(idx / (513LL * 1027));
            int rr = (int)(idx % (513LL * 1027));
            int c  = rr / 1027;
            int t  = rr % 1027;
            const float* xb = x + (size_t)bb * LSAMP;
            const float* fr = fb + (size_t)c * KLEN;
            const float* fi = fb + (size_t)(513 + c) * KLEN;
            const long s = (long)t * HOP - KLEN;
            double re = 0.0, im = 0.0;
            for (int k = lane; k < KLEN; k += 64) {
                long gg = s + k;
                double xv = (gg >= 0 && gg < LSAMP) ? (double)xb[gg] : 0.0;
                re = fma((double)fr[k], xv, re);
                im = fma((double)fi[k], xv, im);
            }
#pragma unroll
            for (int off = 32; off > 0; off >>= 1) {
                re += __shfl_down(re, off);
                im += __shfl_down(im, off);
            }
            if (lane == 0) {
                out[idx]       = (float)sqrt(re * re + im * im + 1e-10);
                out[BCT + idx] = (float)atan2(im, re);
            }
        }
    }
}

// ================= legacy fallback (R3 path, used only if ws too small) =================
__global__ __launch_bounds__(256)
void stft_gemm_legacy(const float* __restrict__ x, const float* __restrict__ fb,
                      float* __restrict__ out) {
    __shared__ unsigned short sml[16384];
    unsigned short* AH = sml;
    unsigned short* AL = sml + 4096;
    unsigned short* BH = sml + 8192;
    unsigned short* BL = sml + 12288;

    const int tid  = threadIdx.x;
    const int lane = tid & 63;
    const int w    = tid >> 6;
    const int wm   = w >> 1;
    const int wn   = w & 1;
    const int lm   = lane & 15;
    const int lk   = (lane >> 4) * 8;

    const int ct = blockIdx.x;
    const int nt = blockIdx.y;
    const int b  = blockIdx.z;
    const int c0 = ct * 64;
    const int n0 = nt * 128;

    const float4* fbg = (const float4*)fb;
    const float*  xb  = x + (size_t)b * LSAMP;

    int srow[4], su[4], sfbrow[4];
    long sxbase0[4];
#pragma unroll
    for (int pp = 0; pp < 4; ++pp) {
        int id = pp * 256 + tid;
        int row = id >> 3, u = id & 7;
        srow[pp] = row; su[pp] = u;
        sfbrow[pp] = (row < 64) ? (c0 + row) : (513 + c0 + (row - 64));
        sxbase0[pp] = 512L * (n0 + row) + 4L * u - 1024L;
    }

    f32x4 acc[4][4];
#pragma unroll
    for (int i = 0; i < 4; ++i)
#pragma unroll
        for (int j = 0; j < 4; ++j) acc[i][j] = (f32x4)0.f;

    float4 pa[4], pb[4];
#pragma unroll
    for (int pp = 0; pp < 4; ++pp) {
        pa[pp] = fbg[(size_t)sfbrow[pp] * 256 + su[pp]];
        long base = sxbase0[pp];
        pb[pp] = (base >= 0 && base < LSAMP) ? *(const float4*)(xb + base)
                                             : make_float4(0.f, 0.f, 0.f, 0.f);
    }

    for (int ks = 0; ks < 32; ++ks) {
        __syncthreads();
#pragma unroll
        for (int pp = 0; pp < 4; ++pp) {
            int o = srow[pp] * 32 + su[pp] * 4;
            float4 va = pa[pp], vb = pb[pp];
            ushort4 h, l;
            h.x = bfh(va.x); l.x = bfh(va.x - bf2f(h.x));
            h.y = bfh(va.y); l.y = bfh(va.y - bf2f(h.y));
            h.z = bfh(va.z); l.z = bfh(va.z - bf2f(h.z));
            h.w = bfh(va.w); l.w = bfh(va.w - bf2f(h.w));
            *(ushort4*)&AH[o] = h; *(ushort4*)&AL[o] = l;
            h.x = bfh(vb.x); l.x = bfh(vb.x - bf2f(h.x));
            h.y = bfh(vb.y); l.y = bfh(vb.y - bf2f(h.y));
            h.z = bfh(vb.z); l.z = bfh(vb.z - bf2f(h.z));
            h.w = bfh(vb.w); l.w = bfh(vb.w - bf2f(h.w));
            *(ushort4*)&BH[o] = h; *(ushort4*)&BL[o] = l;
        }
        __syncthreads();

        if (ks < 31) {
            int k0n = (ks + 1) * 32;
#pragma unroll
            for (int pp = 0; pp < 4; ++pp) {
                pa[pp] = fbg[(size_t)sfbrow[pp] * 256 + (k0n >> 2) + su[pp]];
                long base = sxbase0[pp] + k0n;
                pb[pp] = (base >= 0 && base < LSAMP) ? *(const float4*)(xb + base)
                                                     : make_float4(0.f, 0.f, 0.f, 0.f);
            }
        }

        short8 ah[4], al[4], bh[4], bl[4];
#pragma unroll
        for (int mi = 0; mi < 4; ++mi) {
            int o = (wm * 64 + mi * 16 + lm) * 32 + lk;
            ah[mi] = *(const short8*)&AH[o];
            al[mi] = *(const short8*)&AL[o];
        }
#pragma unroll
        for (int ni = 0; ni < 4; ++ni) {
            int o = (wn * 64 + ni * 16 + lm) * 32 + lk;
            bh[ni] = *(const short8*)&BH[o];
            bl[ni] = *(const short8*)&BL[o];
        }
#pragma unroll
        for (int mi = 0; mi < 4; ++mi)
#pragma unroll
            for (int ni = 0; ni < 4; ++ni)
                acc[mi][ni] = __builtin_amdgcn_mfma_f32_16x16x32_bf16(ah[mi], bh[ni], acc[mi][ni], 0, 0, 0);
#pragma unroll
        for (int mi = 0; mi < 4; ++mi)
#pragma unroll
            for (int ni = 0; ni < 4; ++ni)
                acc[mi][ni] = __builtin_amdgcn_mfma_f32_16x16x32_bf16(ah[mi], bl[ni], acc[mi][ni], 0, 0, 0);
#pragma unroll
        for (int mi = 0; mi < 4; ++mi)
#pragma unroll
            for (int ni = 0; ni < 4; ++ni)
                acc[mi][ni] = __builtin_amdgcn_mfma_f32_16x16x32_bf16(al[mi], bh[ni], acc[mi][ni], 0, 0, 0);
    }

    float* epsRe = (float*)sml;
    float* epsIm = (float*)(sml + 8192);
#pragma unroll
    for (int h = 0; h < 2; ++h) {
        __syncthreads();
#pragma unroll
        for (int mi = 0; mi < 4; ++mi)
#pragma unroll
            for (int nj = 0; nj < 2; ++nj) {
                int ni = 2 * h + nj;
#pragma unroll
                for (int r = 0; r < 4; ++r) {
                    int cr   = mi * 16 + (lane >> 4) * 4 + r;
                    int nbuf = wn * 32 + nj * 16 + lm;
                    if (wm == 0) epsRe[cr * 64 + nbuf] = acc[mi][ni][r];
                    else         epsIm[cr * 64 + nbuf] = acc[mi][ni][r];
                }
            }
        __syncthreads();
#pragma unroll
        for (int qq = 0; qq < 16; ++qq) {
            int id   = qq * 256 + tid;
            int cr   = id >> 6;
            int nbuf = id & 63;
            int nr   = (nbuf >> 5) * 64 + h * 32 + (nbuf & 31);
            int n    = n0 + nr;
            if (n < TWIN) {
                float re = epsRe[cr * 64 + nbuf];
                float im = epsIm[cr * 64 + nbuf];
                size_t base = ((size_t)b * CBIN + (c0 + cr)) * TWIN + n;
                out[base]       = sqrtf(fmaf(re, re, fmaf(im, im, 1e-10f)));
                out[BCT + base] = atan2f(im, re);
            }
        }
    }
}

__global__ __launch_bounds__(256)
void stft_nyq(const float* __restrict__ x, const float* __restrict__ fb,
              float* __restrict__ out) {
    const int gw   = (int)((blockIdx.x * 256 + threadIdx.x) >> 6);
    const int lane = threadIdx.x & 63;
    if (gw >= BATCH * TWIN) return;
    const int b = gw / TWIN;
    const int t = gw % TWIN;
    const long s = (long)t * HOP - KLEN;
    const float* xb = x + (size_t)b * LSAMP;
    const float* frow  = fb + (size_t)512 * KLEN;
    const float* firow = fb + (size_t)1025 * KLEN;

    float re = 0.f, im = 0.f;
    for (int k = lane; k < KLEN; k += 64) {
        long gg = s + k;
        float xv = (gg >= 0 && gg < LSAMP) ? xb[gg] : 0.f;
        re = fmaf(xv, frow[k], re);
        im = fmaf(xv, firow[k], im);
    }
#pragma unroll
    for (int off = 32; off > 0; off >>= 1) {
        re += __shfl_down(re, off);
        im += __shfl_down(im, off);
    }
    if (lane == 0) {
        size_t base = ((size_t)b * CBIN + 512) * TWIN + t;
        out[base]       = sqrtf(fmaf(re, re, fmaf(im, im, 1e-10f)));
        out[BCT + base] = atan2f(im, re);
    }
}

extern "C" void kernel_launch(void* const* d_in, const int* in_sizes, int n_in,
                              void* d_out, int out_size, void* d_ws, size_t ws_size,
                              hipStream_t stream) {
    const float* x  = (const float*)d_in[0];
    const float* fb = (const float*)d_in[1];
    float* out = (float*)d_out;

    if (ws_size >= WS_NEED) {
        unsigned short* ws = (unsigned short*)d_ws;
        split_fb<<<(FBT_SLOTS + 255) / 256, 256, 0, stream>>>(fb, ws);
        split_x<<<(64 * (XPLANE / 8) + 255) / 256, 256, 0, stream>>>(x, ws);
        stft_gemm<<<5184, 256, 67584, stream>>>(ws, out);
        stft_fix<<<2048, 256, 0, stream>>>(x, fb, out);
    } else {
        dim3 grid(8, 9, BATCH);
        stft_gemm_legacy<<<grid, 256, 0, stream>>>(x, fb, out);
        int nwaves = BATCH * TWIN;
        int nblk = (nwaves * 64 + 255) / 256;
        stft_nyq<<<nblk, 256, 0, stream>>>(x, fb, out);
        stft_fix<<<2048, 256, 0, stream>>>(x, fb, out);
    }
}

// Round 5
// 620.735 us; speedup vs baseline: 10.2172x; 1.6803x over previous
//
#include <hip/hip_runtime.h>
#include <math.h>

#define BATCH 64
#define LSAMP 524288
#define KLEN 1024
#define HOP 512
#define CBIN 513
#define TWIN 1027
#define BCT (64LL * 513 * 1027)   // 33718464

typedef unsigned int uint32;
using short8  = __attribute__((ext_vector_type(8))) short;
using ushort8v= __attribute__((ext_vector_type(8))) unsigned short;
using f32x4   = __attribute__((ext_vector_type(4))) float;

// ---- workspace layout (ushort element offsets) ----
#define FBT_SLOTS (9 * 32 * 512)                 // 147456 slots of 8 ushorts
#define FBH_OFF 0u
#define FBL_OFF ((uint32)FBT_SLOTS * 8u)         // 1179648
#define XPLANE  526336                           // 1024 pad + 524288 + 1024 pad
#define XH_OFF  (2u * (uint32)FBT_SLOTS * 8u)    // 2359296
#define XL_OFF  (XH_OFF + 64u * (uint32)XPLANE)  // 36044800
#define WS_NEED ((size_t)(XL_OFF + 64u * (uint32)XPLANE) * 2)  // 139,460,608 B

__device__ __forceinline__ unsigned short bfh(float v) {
    uint32 u = __float_as_uint(v);
    return (unsigned short)((u + 0x7fffu + ((u >> 16) & 1u)) >> 16);   // RNE
}
__device__ __forceinline__ float bf2f(unsigned short h) {
    return __uint_as_float(((uint32)h) << 16);
}

__device__ __forceinline__ void gld16(const void* g, void* l) {
    using GT = const __attribute__((address_space(1))) unsigned int;
    using LT = __attribute__((address_space(3))) unsigned int;
    __builtin_amdgcn_global_load_lds((GT*)g, (LT*)l, 16, 0, 0);
}

// ---------------- pre-pass: split fb into pre-swizzled bf16 hi/lo tiles ----------------
__global__ __launch_bounds__(256)
void split_fb(const float* __restrict__ fb, unsigned short* __restrict__ ws) {
    int id = blockIdx.x * 256 + threadIdx.x;
    if (id >= FBT_SLOTS) return;
    int slot = id & 511;
    int tile = id >> 9;          // ct*32 + ks
    int ks = tile & 31;
    int ct = tile >> 5;
    int row = slot >> 2;
    int unit = (slot & 3) ^ ((row >> 1) & 3);   // logical k-unit stored at this slot
    int c0 = (ct < 8) ? ct * 64 : 449;
    int c = (row < 64) ? (c0 + row) : (513 + c0 + (row - 64));
    int k0 = ks * 32 + unit * 8;
    const float4* src = (const float4*)(fb + (size_t)c * KLEN + k0);
    float4 a = src[0], b = src[1];
    float vv[8] = {a.x, a.y, a.z, a.w, b.x, b.y, b.z, b.w};
    ushort8v hh, ll;
#pragma unroll
    for (int j = 0; j < 8; ++j) {
        unsigned short h = bfh(vv[j]);
        hh[j] = h;
        ll[j] = bfh(vv[j] - bf2f(h));
    }
    *(ushort8v*)&ws[FBH_OFF + (size_t)id * 8] = hh;
    *(ushort8v*)&ws[FBL_OFF + (size_t)id * 8] = ll;
}

// ---------------- pre-pass: split x into zero-padded bf16 hi/lo planes ----------------
__global__ __launch_bounds__(256)
void split_x(const float* __restrict__ x, unsigned short* __restrict__ ws) {
    long i = (long)blockIdx.x * 256 + threadIdx.x;
    if (i >= 64L * (XPLANE / 8)) return;
    int b = (int)(i / (XPLANE / 8));
    int j = (int)(i % (XPLANE / 8)) * 8;      // plane element offset, 8-aligned
    long sample = (long)j - 1024;
    float vv[8] = {0.f,0.f,0.f,0.f,0.f,0.f,0.f,0.f};
    if (sample >= 0 && sample < LSAMP) {
        const float4* s = (const float4*)(x + (size_t)b * LSAMP + sample);
        float4 a = s[0], c = s[1];
        vv[0]=a.x; vv[1]=a.y; vv[2]=a.z; vv[3]=a.w;
        vv[4]=c.x; vv[5]=c.y; vv[6]=c.z; vv[7]=c.w;
    }
    ushort8v hh, ll;
#pragma unroll
    for (int jj = 0; jj < 8; ++jj) {
        unsigned short h = bfh(vv[jj]);
        hh[jj] = h;
        ll[jj] = bfh(vv[jj] - bf2f(h));
    }
    *(ushort8v*)&ws[(size_t)XH_OFF + (size_t)b * XPLANE + j] = hh;
    *(ushort8v*)&ws[(size_t)XL_OFF + (size_t)b * XPLANE + j] = ll;
}

// ---------------- main GEMM: gload_lds staging, dbuf 2-phase, bf16x2 MFMA ----------------
__global__ __launch_bounds__(256, 2)
void stft_gemm(const unsigned short* __restrict__ ws, float* __restrict__ out) {
    extern __shared__ unsigned short sm[];

    const int tid  = threadIdx.x;
    const int lane = tid & 63;
    const int w    = tid >> 6;
    const int wm   = w >> 1;          // 0: re rows, 1: im rows
    const int wn   = w & 1;
    const int lm   = lane & 15;
    const int lg   = lane >> 4;
    const int swz  = (lm >> 1) & 3;

    const int p   = blockIdx.x;
    const int xcd = p & 7;
    const int q   = p >> 3;
    const int ct  = q % 9;
    const int g   = (q / 9) * 8 + xcd;
    const int nt  = g % 9;
    const int b   = g / 9;
    const int c0  = (ct < 8) ? ct * 64 : 449;
    const int n0  = nt * 128;

    f32x4 acc[4][4];
#pragma unroll
    for (int i = 0; i < 4; ++i)
#pragma unroll
        for (int j = 0; j < 4; ++j) acc[i][j] = (f32x4)0.f;

    auto STAGE = [&](int d, int ks) {
        const int s0 = w * 128;
        const uint32 atile = (uint32)(ct * 32 + ks) * 4096u;
#pragma unroll
        for (int r = 0; r < 2; ++r) {
            const int sbase = s0 + r * 64;
            const uint32 slot = (uint32)(sbase + lane);
            const uint32 dsto = (uint32)d * 16384u + (uint32)sbase * 8u;
            gld16(&ws[atile + slot * 8u],            &sm[dsto]);            // AH
            gld16(&ws[FBL_OFF + atile + slot * 8u],  &sm[dsto + 4096u]);    // AL
            const uint32 brow  = slot >> 2;
            const uint32 bunit = (slot & 3u) ^ ((brow >> 1) & 3u);
            uint32 pidx = (uint32)(n0 + brow) * 512u + (uint32)ks * 32u + bunit * 8u;
            if (pidx > (uint32)(XPLANE - 8)) pidx = (uint32)(XPLANE - 8);
            gld16(&ws[(size_t)XH_OFF + (size_t)b * XPLANE + pidx], &sm[dsto + 8192u]);   // BH
            gld16(&ws[(size_t)XL_OFF + (size_t)b * XPLANE + pidx], &sm[dsto + 12288u]);  // BL
        }
    };

    STAGE(0, 0);
    __syncthreads();

    for (int ks = 0; ks < 32; ++ks) {
        const int cur = ks & 1;
        if (ks < 31) STAGE(cur ^ 1, ks + 1);

        const uint32 base = (uint32)cur * 16384u;
        short8 ah[4], al[4], bh[4], bl[4];
#pragma unroll
        for (int mi = 0; mi < 4; ++mi) {
            const uint32 row = (uint32)(wm * 64 + mi * 16 + lm);
            const uint32 o = base + row * 32u + (uint32)((lg ^ swz) * 8);
            ah[mi] = *(const short8*)&sm[o];
            al[mi] = *(const short8*)&sm[o + 4096u];
        }
#pragma unroll
        for (int ni = 0; ni < 4; ++ni) {
            const uint32 row = (uint32)(wn * 64 + ni * 16 + lm);
            const uint32 o = base + 8192u + row * 32u + (uint32)((lg ^ swz) * 8);
            bh[ni] = *(const short8*)&sm[o];
            bl[ni] = *(const short8*)&sm[o + 4096u];
        }
#pragma unroll
        for (int mi = 0; mi < 4; ++mi)
#pragma unroll
            for (int ni = 0; ni < 4; ++ni)
                acc[mi][ni] = __builtin_amdgcn_mfma_f32_16x16x32_bf16(ah[mi], bh[ni], acc[mi][ni], 0, 0, 0);
#pragma unroll
        for (int mi = 0; mi < 4; ++mi)
#pragma unroll
            for (int ni = 0; ni < 4; ++ni)
                acc[mi][ni] = __builtin_amdgcn_mfma_f32_16x16x32_bf16(ah[mi], bl[ni], acc[mi][ni], 0, 0, 0);
#pragma unroll
        for (int mi = 0; mi < 4; ++mi)
#pragma unroll
            for (int ni = 0; ni < 4; ++ni)
                acc[mi][ni] = __builtin_amdgcn_mfma_f32_16x16x32_bf16(al[mi], bh[ni], acc[mi][ni], 0, 0, 0);

        __syncthreads();
    }

    float* eps = (float*)sm;   // [2][64][132] f32
#pragma unroll
    for (int mi = 0; mi < 4; ++mi)
#pragma unroll
        for (int ni = 0; ni < 4; ++ni)
#pragma unroll
            for (int r = 0; r < 4; ++r) {
                int cr = mi * 16 + lg * 4 + r;
                int nc = wn * 64 + ni * 16 + lm;
                eps[wm * 8448 + cr * 132 + nc] = acc[mi][ni][r];
            }
    __syncthreads();
#pragma unroll 4
    for (int qq = 0; qq < 32; ++qq) {
        int id = qq * 256 + tid;
        int cr = id >> 7, nc = id & 127;
        int n = n0 + nc;
        if (n < TWIN) {
            float re = eps[cr * 132 + nc];
            float im = eps[8448 + cr * 132 + nc];
            size_t obase = ((size_t)b * CBIN + (c0 + cr)) * TWIN + n;
            out[obase]       = sqrtf(fmaf(re, re, fmaf(im, im, 1e-10f)));
            out[BCT + obase] = atan2f(im, re);
        }
    }
}

// ---------------- branch-cut cleanup v2: vectorized scan, narrow risky set ----------------
// Excludes: t in {0,1026} (exactly-zero windows, both sides identical);
// c in {0,512} for the pi-cut leg (im sign reliable there; only m<2e-3 kept).
__global__ __launch_bounds__(256)
void stft_fix(const float* __restrict__ x, const float* __restrict__ fb,
              float* __restrict__ out) {
    const int lane = threadIdx.x & 63;
    const uint32 nquad = (uint32)(BCT / 4);                    // 8,429,616
    const uint32 nquad_pad = (nquad + 63u) & ~63u;             // wave-aligned
    const uint32 stride = gridDim.x * 256;
    for (uint32 gq = blockIdx.x * 256 + threadIdx.x; gq < nquad_pad; gq += stride) {
        const bool live = gq < nquad;
        float mm[4] = {1e9f, 1e9f, 1e9f, 1e9f};
        float pp[4] = {0.f, 0.f, 0.f, 0.f};
        if (live) {
            float4 mv = *(const float4*)&out[(size_t)gq * 4];
            float4 pv = *(const float4*)&out[BCT + (size_t)gq * 4];
            mm[0]=mv.x; mm[1]=mv.y; mm[2]=mv.z; mm[3]=mv.w;
            pp[0]=pv.x; pp[1]=pv.y; pp[2]=pv.z; pp[3]=pv.w;
        }
        bool cand = false;
#pragma unroll
        for (int j = 0; j < 4; ++j)
            cand |= (mm[j] < 2e-3f) || ((3.14159265f - fabsf(pp[j])) * mm[j] < 3e-3f);
        if (__ballot(cand) == 0ULL) continue;

        // refine: need t, c of each of the 4 points
        bool risky[4] = {false, false, false, false};
        if (live) {
            uint32 i0  = gq * 4u;
            uint32 row = i0 / 1027u;
            uint32 t0  = i0 - row * 1027u;
            uint32 cc0 = row % 513u;
#pragma unroll
            for (int j = 0; j < 4; ++j) {
                uint32 t = t0 + j, c = cc0;
                if (t >= 1027u) { t -= 1027u; c = (c == 512u) ? 0u : c + 1u; }
                bool edge = (t == 0u) | (t == 1026u);
                bool axis = (c == 0u) | (c == 512u);
                risky[j] = !edge && ((mm[j] < 2e-3f) ||
                                     (!axis && (3.14159265f - fabsf(pp[j])) * mm[j] < 3e-3f));
            }
        }
#pragma unroll
        for (int j = 0; j < 4; ++j) {
            unsigned long long mask = __ballot(risky[j]);
            while (mask) {
                int src = __ffsll(mask) - 1;
                mask &= mask - 1;
                uint32 idx = (gq - lane + (uint32)src) * 4u + (uint32)j;
                uint32 rw = idx / 1027u;
                uint32 t  = idx - rw * 1027u;
                uint32 bb = rw / 513u;
                uint32 c  = rw - bb * 513u;
                const float* xb = x + (size_t)bb * LSAMP;
                const float* fr = fb + (size_t)c * KLEN;
                const float* fi = fb + (size_t)(513 + c) * KLEN;
                const long s = (long)t * HOP - KLEN;
                double re = 0.0, im = 0.0;
                for (int k = lane; k < KLEN; k += 64) {
                    long gg = s + k;
                    double xv = (gg >= 0 && gg < LSAMP) ? (double)xb[gg] : 0.0;
                    re = fma((double)fr[k], xv, re);
                    im = fma((double)fi[k], xv, im);
                }
#pragma unroll
                for (int off = 32; off > 0; off >>= 1) {
                    re += __shfl_down(re, off);
                    im += __shfl_down(im, off);
                }
                if (lane == 0) {
                    out[idx]       = (float)sqrt(re * re + im * im + 1e-10);
                    out[BCT + idx] = (float)atan2(im, re);
                }
            }
        }
    }
}

// ================= legacy fallback (used only if ws too small) =================
__global__ __launch_bounds__(256)
void stft_gemm_legacy(const float* __restrict__ x, const float* __restrict__ fb,
                      float* __restrict__ out) {
    __shared__ unsigned short sml[16384];
    unsigned short* AH = sml;
    unsigned short* AL = sml + 4096;
    unsigned short* BH = sml + 8192;
    unsigned short* BL = sml + 12288;

    const int tid  = threadIdx.x;
    const int lane = tid & 63;
    const int w    = tid >> 6;
    const int wm   = w >> 1;
    const int wn   = w & 1;
    const int lm   = lane & 15;
    const int lk   = (lane >> 4) * 8;

    const int ct = blockIdx.x;
    const int nt = blockIdx.y;
    const int b  = blockIdx.z;
    const int c0 = ct * 64;
    const int n0 = nt * 128;

    const float4* fbg = (const float4*)fb;
    const float*  xb  = x + (size_t)b * LSAMP;

    int srow[4], su[4], sfbrow[4];
    long sxbase0[4];
#pragma unroll
    for (int pp = 0; pp < 4; ++pp) {
        int id = pp * 256 + tid;
        int row = id >> 3, u = id & 7;
        srow[pp] = row; su[pp] = u;
        sfbrow[pp] = (row < 64) ? (c0 + row) : (513 + c0 + (row - 64));
        sxbase0[pp] = 512L * (n0 + row) + 4L * u - 1024L;
    }

    f32x4 acc[4][4];
#pragma unroll
    for (int i = 0; i < 4; ++i)
#pragma unroll
        for (int j = 0; j < 4; ++j) acc[i][j] = (f32x4)0.f;

    float4 pa[4], pb[4];
#pragma unroll
    for (int pp = 0; pp < 4; ++pp) {
        pa[pp] = fbg[(size_t)sfbrow[pp] * 256 + su[pp]];
        long base = sxbase0[pp];
        pb[pp] = (base >= 0 && base < LSAMP) ? *(const float4*)(xb + base)
                                             : make_float4(0.f, 0.f, 0.f, 0.f);
    }

    for (int ks = 0; ks < 32; ++ks) {
        __syncthreads();
#pragma unroll
        for (int pp = 0; pp < 4; ++pp) {
            int o = srow[pp] * 32 + su[pp] * 4;
            float4 va = pa[pp], vb = pb[pp];
            ushort4 h, l;
            h.x = bfh(va.x); l.x = bfh(va.x - bf2f(h.x));
            h.y = bfh(va.y); l.y = bfh(va.y - bf2f(h.y));
            h.z = bfh(va.z); l.z = bfh(va.z - bf2f(h.z));
            h.w = bfh(va.w); l.w = bfh(va.w - bf2f(h.w));
            *(ushort4*)&AH[o] = h; *(ushort4*)&AL[o] = l;
            h.x = bfh(vb.x); l.x = bfh(vb.x - bf2f(h.x));
            h.y = bfh(vb.y); l.y = bfh(vb.y - bf2f(h.y));
            h.z = bfh(vb.z); l.z = bfh(vb.z - bf2f(h.z));
            h.w = bfh(vb.w); l.w = bfh(vb.w - bf2f(h.w));
            *(ushort4*)&BH[o] = h; *(ushort4*)&BL[o] = l;
        }
        __syncthreads();

        if (ks < 31) {
            int k0n = (ks + 1) * 32;
#pragma unroll
            for (int pp = 0; pp < 4; ++pp) {
                pa[pp] = fbg[(size_t)sfbrow[pp] * 256 + (k0n >> 2) + su[pp]];
                long base = sxbase0[pp] + k0n;
                pb[pp] = (base >= 0 && base < LSAMP) ? *(const float4*)(xb + base)
                                                     : make_float4(0.f, 0.f, 0.f, 0.f);
            }
        }

        short8 ah[4], al[4], bh[4], bl[4];
#pragma unroll
        for (int mi = 0; mi < 4; ++mi) {
            int o = (wm * 64 + mi * 16 + lm) * 32 + lk;
            ah[mi] = *(const short8*)&AH[o];
            al[mi] = *(const short8*)&AL[o];
        }
#pragma unroll
        for (int ni = 0; ni < 4; ++ni) {
            int o = (wn * 64 + ni * 16 + lm) * 32 + lk;
            bh[ni] = *(const short8*)&BH[o];
            bl[ni] = *(const short8*)&BL[o];
        }
#pragma unroll
        for (int mi = 0; mi < 4; ++mi)
#pragma unroll
            for (int ni = 0; ni < 4; ++ni)
                acc[mi][ni] = __builtin_amdgcn_mfma_f32_16x16x32_bf16(ah[mi], bh[ni], acc[mi][ni], 0, 0, 0);
#pragma unroll
        for (int mi = 0; mi < 4; ++mi)
#pragma unroll
            for (int ni = 0; ni < 4; ++ni)
                acc[mi][ni] = __builtin_amdgcn_mfma_f32_16x16x32_bf16(ah[mi], bl[ni], acc[mi][ni], 0, 0, 0);
#pragma unroll
        for (int mi = 0; mi < 4; ++mi)
#pragma unroll
            for (int ni = 0; ni < 4; ++ni)
                acc[mi][ni] = __builtin_amdgcn_mfma_f32_16x16x32_bf16(al[mi], bh[ni], acc[mi][ni], 0, 0, 0);
    }

    float* epsRe = (float*)sml;
    float* epsIm = (float*)(sml + 8192);
#pragma unroll
    for (int h = 0; h < 2; ++h) {
        __syncthreads();
#pragma unroll
        for (int mi = 0; mi < 4; ++mi)
#pragma unroll
            for (int nj = 0; nj < 2; ++nj) {
                int ni = 2 * h + nj;
#pragma unroll
                for (int r = 0; r < 4; ++r) {
                    int cr   = mi * 16 + (lane >> 4) * 4 + r;
                    int nbuf = wn * 32 + nj * 16 + lm;
                    if (wm == 0) epsRe[cr * 64 + nbuf] = acc[mi][ni][r];
                    else         epsIm[cr * 64 + nbuf] = acc[mi][ni][r];
                }
            }
        __syncthreads();
#pragma unroll
        for (int qq = 0; qq < 16; ++qq) {
            int id   = qq * 256 + tid;
            int cr   = id >> 6;
            int nbuf = id & 63;
            int nr   = (nbuf >> 5) * 64 + h * 32 + (nbuf & 31);
            int n    = n0 + nr;
            if (n < TWIN) {
                float re = epsRe[cr * 64 + nbuf];
                float im = epsIm[cr * 64 + nbuf];
                size_t base = ((size_t)b * CBIN + (c0 + cr)) * TWIN + n;
                out[base]       = sqrtf(fmaf(re, re, fmaf(im, im, 1e-10f)));
                out[BCT + base] = atan2f(im, re);
            }
        }
    }
}

__global__ __launch_bounds__(256)
void stft_nyq(const float* __restrict__ x, const float* __restrict__ fb,
              float* __restrict__ out) {
    const int gw   = (int)((blockIdx.x * 256 + threadIdx.x) >> 6);
    const int lane = threadIdx.x & 63;
    if (gw >= BATCH * TWIN) return;
    const int b = gw / TWIN;
    const int t = gw % TWIN;
    const long s = (long)t * HOP - KLEN;
    const float* xb = x + (size_t)b * LSAMP;
    const float* frow  = fb + (size_t)512 * KLEN;
    const float* firow = fb + (size_t)1025 * KLEN;

    float re = 0.f, im = 0.f;
    for (int k = lane; k < KLEN; k += 64) {
        long gg = s + k;
        float xv = (gg >= 0 && gg < LSAMP) ? xb[gg] : 0.f;
        re = fmaf(xv, frow[k], re);
        im = fmaf(xv, firow[k], im);
    }
#pragma unroll
    for (int off = 32; off > 0; off >>= 1) {
        re += __shfl_down(re, off);
        im += __shfl_down(im, off);
    }
    if (lane == 0) {
        size_t base = ((size_t)b * CBIN + 512) * TWIN + t;
        out[base]       = sqrtf(fmaf(re, re, fmaf(im, im, 1e-10f)));
        out[BCT + base] = atan2f(im, re);
    }
}

extern "C" void kernel_launch(void* const* d_in, const int* in_sizes, int n_in,
                              void* d_out, int out_size, void* d_ws, size_t ws_size,
                              hipStream_t stream) {
    const float* x  = (const float*)d_in[0];
    const float* fb = (const float*)d_in[1];
    float* out = (float*)d_out;

    if (ws_size >= WS_NEED) {
        unsigned short* ws = (unsigned short*)d_ws;
        split_fb<<<(FBT_SLOTS + 255) / 256, 256, 0, stream>>>(fb, ws);
        split_x<<<(64 * (XPLANE / 8) + 255) / 256, 256, 0, stream>>>(x, ws);
        stft_gemm<<<5184, 256, 67584, stream>>>(ws, out);
        stft_fix<<<2048, 256, 0, stream>>>(x, fb, out);
    } else {
        dim3 grid(8, 9, BATCH);
        stft_gemm_legacy<<<grid, 256, 0, stream>>>(x, fb, out);
        int nwaves = BATCH * TWIN;
        int nblk = (nwaves * 64 + 255) / 256;
        stft_nyq<<<nblk, 256, 0, stream>>>(x, fb, out);
        stft_fix<<<2048, 256, 0, stream>>>(x, fb, out);
    }
}